// Round 4
// baseline (440.873 us; speedup 1.0000x reference)
//
#include <hip/hip_runtime.h>

#define H 512
#define E2d 512
#define NTOK 64
#define NPIX 49
#define CDIM 2048
#define VOCAB 10000

// ws layout (float offsets)
#define WS_SACC   0         // 64x512 acc: x@Wsx + hprev@Wsh   (zeroed)
#define WS_G2     32768     // 64x512 acc: h@Wg2               (zeroed)
#define WS_GA1    65536     // 64x512 acc: s@Wgvs + h@Wghs     (zeroed)
#define WS_GA2    98304     // 64x512 acc: s@Wgvc + h@Wghc     (zeroed)
#define WS_SPAT   131072    // 64x512 acc: c_spatial@Wspat     (zeroed)
#define ZERO_N    163840
#define WS_S      163840    // 64x512 row-major s
#define WS_ST     196608    // 512x64 s^T
#define WS_HT     229376    // 512x64 h^T
#define WS_XT     262144    // 512x64 x^T; later SG
#define WS_SG     262144    // 64x512 s_gate (alias XT)
#define WS_HPT    294912    // 512x64 hprev^T; later CG
#define WS_CG     294912    // 64x512 c_gate (alias HPT)
#define WS_A0     327680    // 64x2048 cxt/alpha0; later CSPT/CHT
#define WS_CSPT   327680    // 2048x64 c_spatial^T (alias)
#define WS_CHT    327680    // 512x64 chat^T (alias)
#define WS_FM     458752    // 8x2048 featmean
#define WS_HWG    475136    // 64x64 (49 used)
#define WS_CS     479232    // 64x64 (49 used)
#define WS_MP     483328    // 4 kc x 64 n x 2401 (k2*49+k) M partials
#define WS_CCP    1097984   // 4 kc x 64 n x 52  cchan partials
// end 1111296 floats = 4.45 MB

#define OUT_ALPHA 640000
#define OUT_BETA  643136

__device__ __forceinline__ float rcp_fast(float x) {
#if __has_builtin(__builtin_amdgcn_rcpf)
  return __builtin_amdgcn_rcpf(x);
#else
  return 1.0f / x;
#endif
}
__device__ __forceinline__ float tanh_f(float x) {
  float e = __expf(2.0f * x);           // inf for large x -> rcp(inf)=0 -> 1
  return 1.0f - 2.0f * rcp_fast(e + 1.0f);
}
__device__ __forceinline__ float sigmoid_f(float x) {
  return rcp_fast(1.0f + __expf(-x));
}

__global__ void k_zero(float* __restrict__ p, int n) {
  int i = blockIdx.x * 256 + threadIdx.x;
  if (i < n) p[i] = 0.0f;
}

// out[n][c] = bmlp[c]
__global__ void k_bias(const float* __restrict__ bmlp, float* __restrict__ out) {
  int c = blockIdx.x * 256 + threadIdx.x, n = blockIdx.y;
  if (c < VOCAB) out[n * VOCAB + c] = bmlp[c];
}

__global__ void k_featmean(const float* __restrict__ V, float* __restrict__ ws) {
  int b = blockIdx.y;
  int c = blockIdx.x * 256 + threadIdx.x;
  float s = 0.0f;
  for (int k = 0; k < NPIX; ++k) s += V[b * NPIX * CDIM + k * CDIM + c];
  ws[WS_FM + b * CDIM + c] = s * (1.0f / NPIX);
}

// transposes: by 0: x -> XT, 1: hid -> HT, 2: hprev -> HPT   (all [512][64])
__global__ void k_tr(const float* __restrict__ x, const float* __restrict__ hid,
                     float* __restrict__ ws) {
  int by = blockIdx.y;
  int idx = blockIdx.x * 256 + threadIdx.x;   // 0..32767
  int n = idx >> 9, k = idx & 511;
  float v;
  float* dst;
  if (by == 0)      { v = x[idx];                                dst = ws + WS_XT; }
  else if (by == 1) { v = hid[idx];                              dst = ws + WS_HT; }
  else              { v = (n & 7) ? hid[idx - 512] : 0.0f;       dst = ws + WS_HPT; }
  dst[k * 64 + n] = v;
}

// ---- multi-token skinny GEMM core: C[64][N] += A^T[K][64] (chunk) @ W[K][N] ----
__device__ __forceinline__ void gemm_body(const float* __restrict__ A,
    const float* __restrict__ W, float* __restrict__ C,
    int k0, int nk, int c, int N) {
  const float4* __restrict__ A4 = (const float4*)A;
  float acc[64];
#pragma unroll
  for (int n = 0; n < 64; ++n) acc[n] = 0.f;
#pragma unroll 2
  for (int kk = 0; kk < nk; ++kk) {
    int k = k0 + kk;
    float w = W[k * N + c];
#pragma unroll
    for (int n4 = 0; n4 < 16; ++n4) {
      float4 a = A4[k * 16 + n4];
      acc[n4 * 4 + 0] += a.x * w;
      acc[n4 * 4 + 1] += a.y * w;
      acc[n4 * 4 + 2] += a.z * w;
      acc[n4 * 4 + 3] += a.w * w;
    }
  }
#pragma unroll
  for (int n = 0; n < 64; ++n) atomicAdd(&C[n * N + c], acc[n]);
}

// SACC += x@Wsx + hprev@Wsh ; grid (2, 32)
__global__ __launch_bounds__(256) void k_gemm_s(const float* __restrict__ Wsx,
    const float* __restrict__ Wsh, float* __restrict__ ws) {
  int c = blockIdx.x * 256 + threadIdx.x;
  int kc = blockIdx.y;
  const float* A = (kc < 16) ? ws + WS_XT : ws + WS_HPT;
  const float* W = (kc < 16) ? Wsx : Wsh;
  gemm_body(A, W, ws + WS_SACC, (kc & 15) * 32, 32, c, 512);
}

// G2 += h@Wg2 ; grid (2, 16)
__global__ __launch_bounds__(256) void k_gemm_g2(const float* __restrict__ Wg2,
    float* __restrict__ ws) {
  int c = blockIdx.x * 256 + threadIdx.x;
  int kc = blockIdx.y;
  gemm_body(ws + WS_HT, Wg2, ws + WS_G2, kc * 32, 32, c, 512);
}

// GA1 += s@Wgvs + h@Wghs ; GA2 += s@Wgvc + h@Wghc ; grid (2, 32, 2)
__global__ __launch_bounds__(256) void k_gemm_gates(const float* __restrict__ Wgvs,
    const float* __restrict__ Wghs, const float* __restrict__ Wgvc,
    const float* __restrict__ Wghc, float* __restrict__ ws) {
  int c = blockIdx.x * 256 + threadIdx.x;
  int kc = blockIdx.y, z = blockIdx.z;
  const float* A = (kc < 16) ? ws + WS_ST : ws + WS_HT;
  const float* W = z ? ((kc < 16) ? Wgvc : Wghc) : ((kc < 16) ? Wgvs : Wghs);
  float* C = ws + (z ? WS_GA2 : WS_GA1);
  gemm_body(A, W, C, (kc & 15) * 32, 32, c, 512);
}

// SPAT += c_spatial@Wspat ; grid (2, 64), K=2048
__global__ __launch_bounds__(256) void k_gemm_spat(const float* __restrict__ Wspat,
    float* __restrict__ ws) {
  int c = blockIdx.x * 256 + threadIdx.x;
  int kc = blockIdx.y;
  gemm_body(ws + WS_CSPT, Wspat, ws + WS_SPAT, kc * 32, 32, c, 512);
}

// out += chat@Wmlp ; grid (40, 8), kchunk 64
__global__ __launch_bounds__(256) void k_gemm_scores(const float* __restrict__ Wmlp,
    float* __restrict__ ws, float* __restrict__ out) {
  int c = blockIdx.x * 256 + threadIdx.x;
  if (c >= VOCAB) return;
  int kc = blockIdx.y;
  gemm_body(ws + WS_CHT, Wmlp, out, kc * 64, 64, c, VOCAB);
}

// s = sigmoid(SACC)*tanh(cells) -> S (row-major) and ST (transposed)
__global__ void k_act_s(const float* __restrict__ cells, float* __restrict__ ws) {
  int idx = blockIdx.x * 256 + threadIdx.x;   // 0..32767
  int n = idx >> 9, c = idx & 511;
  float v = sigmoid_f(ws[WS_SACC + idx]) * tanh_f(cells[idx]);
  ws[WS_S + idx] = v;
  ws[WS_ST + c * 64 + n] = v;
}

// gates: SG = sigmoid(GA1), CG = sigmoid(GA2)
__global__ void k_act_g(float* __restrict__ ws) {
  int idx = blockIdx.x * 256 + threadIdx.x;
  ws[WS_SG + idx] = sigmoid_f(ws[WS_GA1 + idx]);
  ws[WS_CG + idx] = sigmoid_f(ws[WS_GA2 + idx]);
}

// cxt[n][c] = sum_j tanh(fm[b][c]*Wfeat[j] + g2[n][j]) * Wcxt[j]
__global__ __launch_bounds__(256) void k_cxt(const float* __restrict__ Wfeat,
    const float* __restrict__ Wcxt, float* __restrict__ ws) {
  __shared__ float2 fw[512];
  __shared__ float g2l[512];
  int tid = threadIdx.x, n = blockIdx.y, b = n >> 3;
  int c = blockIdx.x * 256 + tid;
  for (int i = tid; i < 512; i += 256) {
    fw[i] = make_float2(Wfeat[i], Wcxt[i]);
    g2l[i] = ws[WS_G2 + n * H + i];
  }
  __syncthreads();
  float fm = ws[WS_FM + b * CDIM + c];
  float acc = 0.0f;
#pragma unroll 4
  for (int j = 0; j < 512; ++j) {
    float2 p = fw[j];
    acc += tanh_f(fm * p.x + g2l[j]) * p.y;
  }
  ws[WS_A0 + n * CDIM + c] = acc;
}

// softmax over 2048, in place on WS_A0
__global__ __launch_bounds__(256) void k_softmax0(float* __restrict__ ws) {
  __shared__ float red[4];
  int n = blockIdx.x, tid = threadIdx.x, lane = tid & 63, w = tid >> 6;
  float* row = ws + WS_A0 + n * CDIM;
  float v[8];
  float m = -1e30f;
#pragma unroll
  for (int i = 0; i < 8; ++i) { v[i] = row[tid + i * 256]; m = fmaxf(m, v[i]); }
  for (int off = 32; off; off >>= 1) m = fmaxf(m, __shfl_xor(m, off));
  if (lane == 0) red[w] = m;
  __syncthreads();
  m = fmaxf(fmaxf(red[0], red[1]), fmaxf(red[2], red[3]));
  float s = 0.0f;
#pragma unroll
  for (int i = 0; i < 8; ++i) { v[i] = __expf(v[i] - m); s += v[i]; }
  for (int off = 32; off; off >>= 1) s += __shfl_xor(s, off);
  __syncthreads();
  if (lane == 0) red[w] = s;
  __syncthreads();
  s = red[0] + red[1] + red[2] + red[3];
  float inv = rcp_fast(s);
#pragma unroll
  for (int i = 0; i < 8; ++i) row[tid + i * 256] = v[i] * inv;
}

// hWg[n][k2] = h@Wg ; CS[n][k2] = s@Ws + h@Wg
// thread = (n, k2); coalesced weight loads, wave-uniform activation loads; no atomics
__global__ __launch_bounds__(256) void k_cs_hwg(const float* __restrict__ hid,
    const float* __restrict__ Wg, const float* __restrict__ Ws_,
    float* __restrict__ ws) {
  int tid = threadIdx.x;
  int n = blockIdx.x * 4 + (tid >> 6);
  int k2 = tid & 63;
  const float* hrow = hid + n * H;
  const float* srow = ws + WS_S + n * H;
  float a1 = 0.0f, a2 = 0.0f;
  if (k2 < NPIX) {
#pragma unroll 4
    for (int e = 0; e < H; ++e) {
      a1 += hrow[e] * Wg[e * NPIX + k2];
      a2 += srow[e] * Ws_[e * NPIX + k2];
    }
    ws[WS_HWG + n * 64 + k2] = a1;
    ws[WS_CS + n * 64 + k2] = a1 + a2;
  }
}

// M partial: Mp[kc][n][k2*49+k] = sum_{c in chunk} alpha0[n][c]*V[b][k][c]*Wv[c][k2]
// + fused cchan partials. grid (4 kc, 64 n), 256 thr. No atomics.
__global__ __launch_bounds__(256) void k_attnM(const float* __restrict__ V,
    const float* __restrict__ Wv, float* __restrict__ ws) {
  __shared__ float a0l[512];
  __shared__ float ul[32 * 52 + 16];
  __shared__ float wl[32 * 52 + 16];
  int tid = threadIdx.x;
  int kc = blockIdx.x, n = blockIdx.y, b = n >> 3;
  int c0 = kc * 512;
  const float* a0 = ws + WS_A0 + n * CDIM + c0;
  const float* Vb = V + b * NPIX * CDIM + c0;
  for (int i = tid; i < 512; i += 256) a0l[i] = a0[i];
  int ti = tid >> 4, tj = tid & 15;   // 4x4 tile at rows 4ti (k), cols 4tj (k2)
  float acc[4][4];
#pragma unroll
  for (int i = 0; i < 4; ++i)
#pragma unroll
    for (int j = 0; j < 4; ++j) acc[i][j] = 0.0f;
  float cch = 0.0f;
  for (int sc = 0; sc < 16; ++sc) {
    __syncthreads();
    int cb = sc * 32;
    // stage u[cc][k] = a0[cb+cc] * V[k][c0+cb+cc]
    for (int idx = tid; idx < NPIX * 32; idx += 256) {
      int k = idx >> 5, cc = idx & 31;
      ul[cc * 52 + k] = a0l[cb + cc] * Vb[k * CDIM + cb + cc];
    }
    // stage Wv[cc][k2]
    for (int idx = tid; idx < 2048; idx += 256) {
      int cc = idx >> 6, r = idx & 63;
      if (r < NPIX) wl[cc * 52 + r] = Wv[(c0 + cb + cc) * NPIX + r];
    }
    __syncthreads();
    if (tid < NPIX) {
#pragma unroll 8
      for (int cc = 0; cc < 32; ++cc) cch += ul[cc * 52 + tid];
    }
#pragma unroll 4
    for (int cc = 0; cc < 32; ++cc) {
      float4 a = *(const float4*)&ul[cc * 52 + 4 * ti];
      float4 w = *(const float4*)&wl[cc * 52 + 4 * tj];
      acc[0][0] += a.x * w.x; acc[0][1] += a.x * w.y; acc[0][2] += a.x * w.z; acc[0][3] += a.x * w.w;
      acc[1][0] += a.y * w.x; acc[1][1] += a.y * w.y; acc[1][2] += a.y * w.z; acc[1][3] += a.y * w.w;
      acc[2][0] += a.z * w.x; acc[2][1] += a.z * w.y; acc[2][2] += a.z * w.z; acc[2][3] += a.z * w.w;
      acc[3][0] += a.w * w.x; acc[3][1] += a.w * w.y; acc[3][2] += a.w * w.z; acc[3][3] += a.w * w.w;
    }
  }
  float* Mp = ws + WS_MP + (kc * 64 + n) * 2401;
#pragma unroll
  for (int jj = 0; jj < 4; ++jj) {
    int k2 = 4 * tj + jj;
    if (k2 < NPIX) {
#pragma unroll
      for (int ii = 0; ii < 4; ++ii) {
        int k = 4 * ti + ii;
        if (k < NPIX) Mp[k2 * 49 + k] = acc[ii][jj];
      }
    }
  }
  if (tid < NPIX) ws[WS_CCP + (kc * 64 + n) * 52 + tid] = cch * (1.0f / CDIM);
}

// z_t, alpha_t (out), z_ext, beta (out); sums 4 M partials
__global__ __launch_bounds__(64) void k_zt(const float* __restrict__ Wh,
    float* __restrict__ ws, float* __restrict__ out) {
  __shared__ float gl[NPIX], whl[NPIX];
  int n = blockIdx.x, lane = threadIdx.x;
  if (lane < NPIX) {
    gl[lane] = ws[WS_HWG + n * 64 + lane];
    whl[lane] = Wh[lane];
  }
  __syncthreads();
  const float* M0 = ws + WS_MP + (0 * 64 + n) * 2401;
  const float* M1 = ws + WS_MP + (1 * 64 + n) * 2401;
  const float* M2 = ws + WS_MP + (2 * 64 + n) * 2401;
  const float* M3 = ws + WS_MP + (3 * 64 + n) * 2401;
  float z = 0.0f;
  if (lane < NPIX) {
    for (int k2 = 0; k2 < NPIX; ++k2) {
      int o = k2 * 49 + lane;
      float m = M0[o] + M1[o] + M2[o] + M3[o];
      z += tanh_f(tanh_f(m + gl[k2])) * whl[k2];
    }
  }
  float zm = (lane < NPIX) ? z : -1e30f;
  float m1 = zm;
  for (int off = 32; off; off >>= 1) m1 = fmaxf(m1, __shfl_xor(m1, off));
  float e = (lane < NPIX) ? __expf(z - m1) : 0.0f;
  float S1 = e;
  for (int off = 32; off; off >>= 1) S1 += __shfl_xor(S1, off);
  if (lane < NPIX) out[OUT_ALPHA + n * NPIX + lane] = e * rcp_fast(S1);
  float vz = (lane < NPIX) ? tanh_f(ws[WS_CS + n * 64 + lane]) * whl[lane] : 0.0f;
  for (int off = 32; off; off >>= 1) vz += __shfl_xor(vz, off);
  if (lane == 0) {
    float ze = vz;
    float m2 = fmaxf(m1, ze);
    float S2 = S1 * __expf(m1 - m2) + __expf(ze - m2);
    out[OUT_BETA + n] = __expf(ze - m2) * rcp_fast(S2);
  }
}

// c_spatial^T[d][n] = sum_k alpha_t[n][k] * V[b][k][d]
__global__ __launch_bounds__(256) void k_cspatial(const float* __restrict__ V,
    const float* __restrict__ out, float* __restrict__ ws) {
  __shared__ float al[NPIX];
  int tid = threadIdx.x, n = blockIdx.y, b = n >> 3;
  int d = blockIdx.x * 256 + tid;
  if (tid < NPIX) al[tid] = out[OUT_ALPHA + n * NPIX + tid];
  __syncthreads();
  float s = 0.0f;
#pragma unroll 7
  for (int k = 0; k < NPIX; ++k) s += al[k] * V[b * NPIX * CDIM + k * CDIM + d];
  ws[WS_CSPT + d * 64 + n] = s;
}

// chat^T[c][n] = s_gate*spat + c_gate*(cchan@Wchan) + h ; sums 4 cchan partials
__global__ __launch_bounds__(256) void k_chat(const float* __restrict__ hid,
    const float* __restrict__ Wchan, float* __restrict__ ws) {
  __shared__ float cl[NPIX];
  int tid = threadIdx.x, n = blockIdx.y;
  int c = blockIdx.x * 256 + tid;
  if (tid < NPIX) {
    cl[tid] = ws[WS_CCP + (0 * 64 + n) * 52 + tid]
            + ws[WS_CCP + (1 * 64 + n) * 52 + tid]
            + ws[WS_CCP + (2 * 64 + n) * 52 + tid]
            + ws[WS_CCP + (3 * 64 + n) * 52 + tid];
  }
  __syncthreads();
  float acc = 0.0f;
#pragma unroll 7
  for (int k = 0; k < NPIX; ++k) acc += cl[k] * Wchan[k * H + c];
  float chat = ws[WS_SG + n * H + c] * ws[WS_SPAT + n * H + c]
             + ws[WS_CG + n * H + c] * acc + hid[n * H + c];
  ws[WS_CHT + c * 64 + n] = chat;
}

extern "C" void kernel_launch(void* const* d_in, const int* in_sizes, int n_in,
                              void* d_out, int out_size, void* d_ws, size_t ws_size,
                              hipStream_t stream) {
  const float* x     = (const float*)d_in[0];
  const float* hid   = (const float*)d_in[1];
  const float* cells = (const float*)d_in[2];
  const float* V     = (const float*)d_in[3];
  const float* Wsx   = (const float*)d_in[4];
  const float* Wsh   = (const float*)d_in[5];
  const float* Wv    = (const float*)d_in[6];
  const float* Wg    = (const float*)d_in[7];
  const float* Ws_   = (const float*)d_in[8];
  const float* Wh    = (const float*)d_in[9];
  const float* Wfeat = (const float*)d_in[10];
  const float* Wcxt  = (const float*)d_in[11];
  const float* Wg2   = (const float*)d_in[12];
  const float* Wspat = (const float*)d_in[13];
  const float* Wchan = (const float*)d_in[14];
  const float* Wgvs  = (const float*)d_in[15];
  const float* Wgvc  = (const float*)d_in[16];
  const float* Wghs  = (const float*)d_in[17];
  const float* Wghc  = (const float*)d_in[18];
  const float* Wmlp  = (const float*)d_in[19];
  const float* bmlp  = (const float*)d_in[20];
  float* ws  = (float*)d_ws;
  float* out = (float*)d_out;

  hipLaunchKernelGGL(k_zero, dim3(ZERO_N / 256), dim3(256), 0, stream, ws, ZERO_N);
  hipLaunchKernelGGL(k_bias, dim3(40, 64), dim3(256), 0, stream, bmlp, out);
  hipLaunchKernelGGL(k_featmean, dim3(8, 8), dim3(256), 0, stream, V, ws);
  hipLaunchKernelGGL(k_tr, dim3(128, 3), dim3(256), 0, stream, x, hid, ws);
  hipLaunchKernelGGL(k_gemm_s, dim3(2, 32), dim3(256), 0, stream, Wsx, Wsh, ws);
  hipLaunchKernelGGL(k_act_s, dim3(128), dim3(256), 0, stream, cells, ws);
  hipLaunchKernelGGL(k_gemm_g2, dim3(2, 16), dim3(256), 0, stream, Wg2, ws);
  hipLaunchKernelGGL(k_cxt, dim3(8, 64), dim3(256), 0, stream, Wfeat, Wcxt, ws);
  hipLaunchKernelGGL(k_softmax0, dim3(64), dim3(256), 0, stream, ws);
  hipLaunchKernelGGL(k_cs_hwg, dim3(16), dim3(256), 0, stream, hid, Wg, Ws_, ws);
  hipLaunchKernelGGL(k_attnM, dim3(4, 64), dim3(256), 0, stream, V, Wv, ws);
  hipLaunchKernelGGL(k_zt, dim3(64), dim3(64), 0, stream, Wh, ws, out);
  hipLaunchKernelGGL(k_cspatial, dim3(8, 64), dim3(256), 0, stream, V, out, ws);
  hipLaunchKernelGGL(k_gemm_gates, dim3(2, 32, 2), dim3(256), 0, stream, Wgvs, Wghs, Wgvc, Wghc, ws);
  hipLaunchKernelGGL(k_act_g, dim3(128), dim3(256), 0, stream, ws);
  hipLaunchKernelGGL(k_gemm_spat, dim3(2, 64), dim3(256), 0, stream, Wspat, ws);
  hipLaunchKernelGGL(k_chat, dim3(2, 64), dim3(256), 0, stream, hid, Wchan, ws);
  hipLaunchKernelGGL(k_gemm_scores, dim3(40, 8), dim3(256), 0, stream, Wmlp, ws, out);
}

// Round 5
// 323.335 us; speedup vs baseline: 1.3635x; 1.3635x over previous
//
#include <hip/hip_runtime.h>

#define H 512
#define NTOK 64
#define NPIX 49
#define CDIM 2048
#define VOCAB 10000

// ws layout (float offsets)
#define WS_SACC   0         // 64x512 acc (zeroed)
#define WS_G2     32768     // 64x512 acc (zeroed)
#define WS_GA1    65536     // 64x512 acc (zeroed, re-zeroed in cspatial)
#define WS_GA2    98304     // 64x512 acc (zeroed, re-zeroed in cspatial)
#define WS_SPAT   131072    // 64x512 acc (zeroed, re-zeroed in cspatial)
#define WS_MM     163840    // 64 x 2401 M accumulator (zeroed)
#define WS_CCHAN  317504    // 64 x 52 (zeroed)
#define ZERO_N    320832
#define WS_S      320832    // 64x512
#define WS_ST     353600    // 512x64
#define WS_HT     386368    // 512x64
#define WS_XT     419136    // 512x64 (dead after gemm_sg2)
#define WS_HPT    451904    // 512x64 (dead after gemm_sg2)
#define WS_A0     484672    // 64x2048 cxt/alpha0; later CSPT; later CHT
#define WS_CSPT   484672    // 2048x64 (alias, after attnM)
#define WS_CHT    484672    // 512x64 (alias, after gemm_gsp)
#define WS_FM     615744    // 8x2048
#define WS_P1     632128    // 8 kc x 64 n x 64 (h@Wg partials)
#define WS_P2     664896    // 8 kc x 64 n x 64 (s@Ws partials)
// end 697664 floats = 2.8 MB

#define OUT_ALPHA 640000
#define OUT_BETA  643136

__device__ __forceinline__ float rcp_fast(float x) {
#if __has_builtin(__builtin_amdgcn_rcpf)
  return __builtin_amdgcn_rcpf(x);
#else
  return 1.0f / x;
#endif
}
__device__ __forceinline__ float tanh_f(float x) {
  float e = __expf(2.0f * x);
  return 1.0f - 2.0f * rcp_fast(e + 1.0f);
}
__device__ __forceinline__ float sigmoid_f(float x) {
  return rcp_fast(1.0f + __expf(-x));
}

// prep: zero accums | bias -> out | featmean | transposes x/h/hprev
#define PREP_Z 1254
#define PREP_B (PREP_Z + 2500)
#define PREP_F (PREP_B + 64)
#define PREP_T (PREP_F + 384)
__global__ __launch_bounds__(256) void k_prep(const float* __restrict__ x,
    const float* __restrict__ hid, const float* __restrict__ V,
    const float* __restrict__ bmlp, float* __restrict__ ws,
    float* __restrict__ out) {
  int bid = blockIdx.x, tid = threadIdx.x;
  if (bid < PREP_Z) {
    int i = bid * 256 + tid;
    if (i < ZERO_N) ws[i] = 0.0f;
  } else if (bid < PREP_B) {
    int idx = (bid - PREP_Z) * 256 + tid;
    int n = idx / VOCAB, c = idx - n * VOCAB;
    if (n < 64) out[idx] = bmlp[c];
  } else if (bid < PREP_F) {
    int b2 = bid - PREP_B;
    int b = b2 >> 3, c = (b2 & 7) * 256 + tid;
    float s = 0.0f;
    for (int k = 0; k < NPIX; ++k) s += V[b * NPIX * CDIM + k * CDIM + c];
    ws[WS_FM + b * CDIM + c] = s * (1.0f / NPIX);
  } else {
    int i3 = (bid - PREP_F) * 256 + tid;
    int role = i3 >> 15, idx = i3 & 32767;
    int n = idx >> 9, k = idx & 511;
    if (role == 0)      ws[WS_XT + k * 64 + n] = x[idx];
    else if (role == 1) ws[WS_HT + k * 64 + n] = hid[idx];
    else                ws[WS_HPT + k * 64 + n] = (n & 7) ? hid[idx - 512] : 0.0f;
  }
}

// acc[16] gemm: C[n0..n0+16][c] += sum_{k0..k0+nk} A^T[k][n] * W[k][N] ; N=512
__device__ __forceinline__ void gemm16(const float* __restrict__ A,
    const float* __restrict__ W, float* __restrict__ C,
    int n0, int k0, int nk, int c) {
  float acc[16];
#pragma unroll
  for (int j = 0; j < 16; ++j) acc[j] = 0.0f;
#pragma unroll 4
  for (int kk = 0; kk < nk; ++kk) {
    int k = k0 + kk;
    float w = W[k * 512 + c];
    const float4* A4 = (const float4*)(A + k * 64 + n0);
#pragma unroll
    for (int q = 0; q < 4; ++q) {
      float4 a = A4[q];
      acc[q * 4 + 0] += a.x * w;
      acc[q * 4 + 1] += a.y * w;
      acc[q * 4 + 2] += a.z * w;
      acc[q * 4 + 3] += a.w * w;
    }
  }
#pragma unroll
  for (int j = 0; j < 16; ++j) atomicAdd(&C[(n0 + j) * 512 + c], acc[j]);
}

// streams: 0:(XT,Wsx,SACC) 1:(HPT,Wsh,SACC) 2:(HT,Wg2,G2); grid (2,8,12)
__global__ __launch_bounds__(256) void k_gemm_sg2(const float* __restrict__ Wsx,
    const float* __restrict__ Wsh, const float* __restrict__ Wg2,
    float* __restrict__ ws) {
  int c = blockIdx.x * 256 + threadIdx.x;
  int k0 = blockIdx.y * 64;
  int z = blockIdx.z, st = z >> 2, n0 = (z & 3) * 16;
  const float* A = (st == 0) ? ws + WS_XT : (st == 1) ? ws + WS_HPT : ws + WS_HT;
  const float* W = (st == 0) ? Wsx : (st == 1) ? Wsh : Wg2;
  float* C = ws + ((st == 2) ? WS_G2 : WS_SACC);
  gemm16(A, W, C, n0, k0, 64, c);
}

// gates+spat: 0:(ST,Wgvs,GA1) 1:(HT,Wghs,GA1) 2:(ST,Wgvc,GA2) 3:(HT,Wghc,GA2)
// 4..7: (CSPT+q*512*64, Wspat+q*512*512, SPAT) ; grid (2,8,32)
__global__ __launch_bounds__(256) void k_gemm_gsp(const float* __restrict__ Wgvs,
    const float* __restrict__ Wghs, const float* __restrict__ Wgvc,
    const float* __restrict__ Wghc, const float* __restrict__ Wspat,
    float* __restrict__ ws) {
  int c = blockIdx.x * 256 + threadIdx.x;
  int k0 = blockIdx.y * 64;
  int z = blockIdx.z, st = z >> 2, n0 = (z & 3) * 16;
  const float* A;
  const float* W;
  float* C;
  if (st < 4) {
    A = ws + ((st & 1) ? WS_HT : WS_ST);
    W = (st == 0) ? Wgvs : (st == 1) ? Wghs : (st == 2) ? Wgvc : Wghc;
    C = ws + ((st < 2) ? WS_GA1 : WS_GA2);
  } else {
    int q = st - 4;
    A = ws + WS_CSPT + q * 512 * 64;
    W = Wspat + q * 512 * 512;
    C = ws + WS_SPAT;
  }
  gemm16(A, W, C, n0, k0, 64, c);
}

// scores: out[n][c] += chat^T @ Wmlp ; acc[64], grid (40,16), nk=32
__global__ __launch_bounds__(256) void k_gemm_scores(const float* __restrict__ Wmlp,
    float* __restrict__ ws, float* __restrict__ out) {
  int c = blockIdx.x * 256 + threadIdx.x;
  if (c >= VOCAB) return;
  int k0 = blockIdx.y * 32;
  const float* A = ws + WS_CHT;
  float acc[64];
#pragma unroll
  for (int n = 0; n < 64; ++n) acc[n] = 0.0f;
#pragma unroll 2
  for (int kk = 0; kk < 32; ++kk) {
    int k = k0 + kk;
    float w = Wmlp[k * VOCAB + c];
    const float4* A4 = (const float4*)(A + k * 64);
#pragma unroll
    for (int q = 0; q < 16; ++q) {
      float4 a = A4[q];
      acc[q * 4 + 0] += a.x * w;
      acc[q * 4 + 1] += a.y * w;
      acc[q * 4 + 2] += a.z * w;
      acc[q * 4 + 3] += a.w * w;
    }
  }
#pragma unroll
  for (int n = 0; n < 64; ++n) atomicAdd(&out[n * VOCAB + c], acc[n]);
}

// s = sigmoid(SACC)*tanh(cells) -> S and ST
__global__ void k_act_s(const float* __restrict__ cells, float* __restrict__ ws) {
  int idx = blockIdx.x * 256 + threadIdx.x;
  int n = idx >> 9, c = idx & 511;
  float v = sigmoid_f(ws[WS_SACC + idx]) * tanh_f(cells[idx]);
  ws[WS_S + idx] = v;
  ws[WS_ST + c * 64 + n] = v;
}

// cxt[n][c] = sum_j tanh(fm[b][c]*Wfeat[j] + g2[n][j]) * Wcxt[j]
__global__ __launch_bounds__(256) void k_cxt(const float* __restrict__ Wfeat,
    const float* __restrict__ Wcxt, float* __restrict__ ws) {
  __shared__ float2 fw[512];
  __shared__ float g2l[512];
  int tid = threadIdx.x, n = blockIdx.y, b = n >> 3;
  int c = blockIdx.x * 256 + tid;
  for (int i = tid; i < 512; i += 256) {
    fw[i] = make_float2(Wfeat[i], Wcxt[i]);
    g2l[i] = ws[WS_G2 + n * H + i];
  }
  __syncthreads();
  float fm = ws[WS_FM + b * CDIM + c];
  float acc = 0.0f;
#pragma unroll 4
  for (int j = 0; j < 512; ++j) {
    float2 p = fw[j];
    acc += tanh_f(fm * p.x + g2l[j]) * p.y;
  }
  ws[WS_A0 + n * CDIM + c] = acc;
}

// bid<64: softmax over A0 row. bid>=64: cs_hwg partials (n, half), wave=kc
__global__ __launch_bounds__(256) void k_softmax_cshwg(const float* __restrict__ hid,
    const float* __restrict__ Wg, const float* __restrict__ Ws_,
    float* __restrict__ ws) {
  int bid = blockIdx.x, tid = threadIdx.x;
  if (bid < 64) {
    __shared__ float red[4];
    int n = bid, lane = tid & 63, w = tid >> 6;
    float* row = ws + WS_A0 + n * CDIM;
    float v[8];
    float m = -1e30f;
#pragma unroll
    for (int i = 0; i < 8; ++i) { v[i] = row[tid + i * 256]; m = fmaxf(m, v[i]); }
    for (int off = 32; off; off >>= 1) m = fmaxf(m, __shfl_xor(m, off));
    if (lane == 0) red[w] = m;
    __syncthreads();
    m = fmaxf(fmaxf(red[0], red[1]), fmaxf(red[2], red[3]));
    float s = 0.0f;
#pragma unroll
    for (int i = 0; i < 8; ++i) { v[i] = __expf(v[i] - m); s += v[i]; }
    for (int off = 32; off; off >>= 1) s += __shfl_xor(s, off);
    __syncthreads();
    if (lane == 0) red[w] = s;
    __syncthreads();
    s = red[0] + red[1] + red[2] + red[3];
    float inv = rcp_fast(s);
#pragma unroll
    for (int i = 0; i < 8; ++i) row[tid + i * 256] = v[i] * inv;
  } else {
    int bidx = bid - 64;
    int n = bidx & 63, half = bidx >> 6;
    int k2 = tid & 63, w = tid >> 6;
    int kc = half * 4 + w;
    const float* hrow = hid + n * H;
    const float* srow = ws + WS_S + n * H;
    float a1 = 0.0f, a2 = 0.0f;
#pragma unroll 4
    for (int kk = 0; kk < 64; ++kk) {
      int k = kc * 64 + kk;
      if (k2 < NPIX) {
        a1 += hrow[k] * Wg[k * NPIX + k2];
        a2 += srow[k] * Ws_[k * NPIX + k2];
      }
    }
    if (k2 < NPIX) {
      ws[WS_P1 + (kc * 64 + n) * 64 + k2] = a1;
      ws[WS_P2 + (kc * 64 + n) * 64 + k2] = a2;
    }
  }
}

// attnM: grid (16 cchunk, 64 n). vl = a0*V staged (one barrier), wl = Wv.
// M[n][k2*49+k] += acc via atomics; cchan fused.
__global__ __launch_bounds__(256) void k_attnM(const float* __restrict__ V,
    const float* __restrict__ Wv, float* __restrict__ ws) {
  __shared__ float vl[128 * 52];
  __shared__ float wl[128 * 52];
  int tid = threadIdx.x;
  int kc = blockIdx.x, n = blockIdx.y, b = n >> 3;
  int c0 = kc * 128;
  const float* a0 = ws + WS_A0 + n * CDIM + c0;
  const float* Vb = V + b * NPIX * CDIM + c0;
  for (int idx = tid; idx < NPIX * 128; idx += 256) {
    int k = idx >> 7, cc = idx & 127;
    vl[cc * 52 + k] = a0[cc] * Vb[k * CDIM + cc];
  }
  for (int idx = tid; idx < 128 * 64; idx += 256) {
    int cc = idx >> 6, r = idx & 63;
    if (r < NPIX) wl[cc * 52 + r] = Wv[(c0 + cc) * NPIX + r];
  }
  __syncthreads();
  // cchan partial
  if (tid < NPIX) {
    float cch = 0.0f;
#pragma unroll 8
    for (int cc = 0; cc < 128; ++cc) cch += vl[cc * 52 + tid];
    atomicAdd(&ws[WS_CCHAN + n * 52 + tid], cch * (1.0f / CDIM));
  }
  int ti = tid >> 4, tj = tid & 15;
  if (ti < 13 && tj < 13) {
    float acc[4][4];
#pragma unroll
    for (int i = 0; i < 4; ++i)
#pragma unroll
      for (int j = 0; j < 4; ++j) acc[i][j] = 0.0f;
#pragma unroll 4
    for (int cc = 0; cc < 128; ++cc) {
      float4 a = *(const float4*)&vl[cc * 52 + 4 * ti];
      float4 w = *(const float4*)&wl[cc * 52 + 4 * tj];
      acc[0][0] += a.x * w.x; acc[0][1] += a.x * w.y; acc[0][2] += a.x * w.z; acc[0][3] += a.x * w.w;
      acc[1][0] += a.y * w.x; acc[1][1] += a.y * w.y; acc[1][2] += a.y * w.z; acc[1][3] += a.y * w.w;
      acc[2][0] += a.z * w.x; acc[2][1] += a.z * w.y; acc[2][2] += a.z * w.z; acc[2][3] += a.z * w.w;
      acc[3][0] += a.w * w.x; acc[3][1] += a.w * w.y; acc[3][2] += a.w * w.z; acc[3][3] += a.w * w.w;
    }
    float* M = ws + WS_MM + n * 2401;
#pragma unroll
    for (int jj = 0; jj < 4; ++jj) {
      int k2 = 4 * tj + jj;
      if (k2 < NPIX) {
#pragma unroll
        for (int ii = 0; ii < 4; ++ii) {
          int k = 4 * ti + ii;
          if (k < NPIX) atomicAdd(&M[k2 * 49 + k], acc[ii][jj]);
        }
      }
    }
  }
}

// zt: phase0 reduce P1/P2 -> gl/cl; phase1 z[k] = sum_k2 f(M); phase2 softmax/beta
__global__ __launch_bounds__(256) void k_zt(const float* __restrict__ Wh,
    float* __restrict__ ws, float* __restrict__ out) {
  __shared__ float gl[NPIX], cl[NPIX], whl[64];
  __shared__ float zbuf[4][64];
  int n = blockIdx.x, tid = threadIdx.x;
  if (tid < NPIX) {
    float s1 = 0.0f, s2 = 0.0f;
#pragma unroll
    for (int kc = 0; kc < 8; ++kc) {
      s1 += ws[WS_P1 + (kc * 64 + n) * 64 + tid];
      s2 += ws[WS_P2 + (kc * 64 + n) * 64 + tid];
    }
    gl[tid] = s1;
    cl[tid] = s1 + s2;
    whl[tid] = Wh[tid];
  }
  __syncthreads();
  int k = tid & 63, g = tid >> 6;
  float zp = 0.0f;
  if (k < NPIX) {
    int k2e = (g == 3) ? NPIX : (g * 13 + 13);
    const float* M = ws + WS_MM + n * 2401;
    for (int k2 = g * 13; k2 < k2e; ++k2) {
      float m = M[k2 * 49 + k];
      zp += tanh_f(tanh_f(m + gl[k2])) * whl[k2];
    }
  }
  zbuf[g][k] = zp;
  __syncthreads();
  if (tid < 64) {
    int lane = tid;
    float z = zbuf[0][lane] + zbuf[1][lane] + zbuf[2][lane] + zbuf[3][lane];
    float zm = (lane < NPIX) ? z : -1e30f;
    float m1 = zm;
    for (int off = 32; off; off >>= 1) m1 = fmaxf(m1, __shfl_xor(m1, off));
    float e = (lane < NPIX) ? __expf(z - m1) : 0.0f;
    float S1 = e;
    for (int off = 32; off; off >>= 1) S1 += __shfl_xor(S1, off);
    if (lane < NPIX) out[OUT_ALPHA + n * NPIX + lane] = e * rcp_fast(S1);
    float vz = (lane < NPIX) ? tanh_f(cl[lane]) * whl[lane] : 0.0f;
    for (int off = 32; off; off >>= 1) vz += __shfl_xor(vz, off);
    if (lane == 0) {
      float ze = vz;
      float m2 = fmaxf(m1, ze);
      float S2 = S1 * __expf(m1 - m2) + __expf(ze - m2);
      out[OUT_BETA + n] = __expf(ze - m2) * rcp_fast(S2);
    }
  }
}

// bid<512: c_spatial^T[d][n]; bid>=512: zero GA1/GA2/SPAT (contiguous 98304)
__global__ __launch_bounds__(256) void k_cspatial(const float* __restrict__ V,
    const float* __restrict__ out, float* __restrict__ ws) {
  int bid = blockIdx.x, tid = threadIdx.x;
  if (bid < 512) {
    __shared__ float al[NPIX];
    int n = bid & 63, b = n >> 3;
    int d = (bid >> 6) * 256 + tid;
    if (tid < NPIX) al[tid] = out[OUT_ALPHA + n * NPIX + tid];
    __syncthreads();
    float s = 0.0f;
#pragma unroll 7
    for (int k = 0; k < NPIX; ++k) s += al[k] * V[b * NPIX * CDIM + k * CDIM + d];
    ws[WS_CSPT + d * 64 + n] = s;
  } else {
    int idx = (bid - 512) * 256 + tid;
    if (idx < 98304) ws[WS_GA1 + idx] = 0.0f;
  }
}

// chat^T[c][n] = sigmoid(GA1)*SPAT + sigmoid(GA2)*(cchan@Wchan) + h
__global__ __launch_bounds__(256) void k_chat(const float* __restrict__ hid,
    const float* __restrict__ Wchan, float* __restrict__ ws) {
  __shared__ float cl[NPIX];
  int tid = threadIdx.x, n = blockIdx.y;
  int c = blockIdx.x * 256 + tid;
  if (tid < NPIX) cl[tid] = ws[WS_CCHAN + n * 52 + tid];
  __syncthreads();
  float acc = 0.0f;
#pragma unroll 7
  for (int k = 0; k < NPIX; ++k) acc += cl[k] * Wchan[k * H + c];
  int idx = n * H + c;
  float chat = sigmoid_f(ws[WS_GA1 + idx]) * ws[WS_SPAT + idx]
             + sigmoid_f(ws[WS_GA2 + idx]) * acc + hid[idx];
  ws[WS_CHT + c * 64 + n] = chat;
}

extern "C" void kernel_launch(void* const* d_in, const int* in_sizes, int n_in,
                              void* d_out, int out_size, void* d_ws, size_t ws_size,
                              hipStream_t stream) {
  const float* x     = (const float*)d_in[0];
  const float* hid   = (const float*)d_in[1];
  const float* cells = (const float*)d_in[2];
  const float* V     = (const float*)d_in[3];
  const float* Wsx   = (const float*)d_in[4];
  const float* Wsh   = (const float*)d_in[5];
  const float* Wv    = (const float*)d_in[6];
  const float* Wg    = (const float*)d_in[7];
  const float* Ws_   = (const float*)d_in[8];
  const float* Wh    = (const float*)d_in[9];
  const float* Wfeat = (const float*)d_in[10];
  const float* Wcxt  = (const float*)d_in[11];
  const float* Wg2   = (const float*)d_in[12];
  const float* Wspat = (const float*)d_in[13];
  const float* Wchan = (const float*)d_in[14];
  const float* Wgvs  = (const float*)d_in[15];
  const float* Wgvc  = (const float*)d_in[16];
  const float* Wghs  = (const float*)d_in[17];
  const float* Wghc  = (const float*)d_in[18];
  const float* Wmlp  = (const float*)d_in[19];
  const float* bmlp  = (const float*)d_in[20];
  float* ws  = (float*)d_ws;
  float* out = (float*)d_out;

  hipLaunchKernelGGL(k_prep, dim3(PREP_T), dim3(256), 0, stream, x, hid, V, bmlp, ws, out);
  hipLaunchKernelGGL(k_gemm_sg2, dim3(2, 8, 12), dim3(256), 0, stream, Wsx, Wsh, Wg2, ws);
  hipLaunchKernelGGL(k_act_s, dim3(128), dim3(256), 0, stream, cells, ws);
  hipLaunchKernelGGL(k_cxt, dim3(8, 64), dim3(256), 0, stream, Wfeat, Wcxt, ws);
  hipLaunchKernelGGL(k_softmax_cshwg, dim3(192), dim3(256), 0, stream, hid, Wg, Ws_, ws);
  hipLaunchKernelGGL(k_attnM, dim3(16, 64), dim3(256), 0, stream, V, Wv, ws);
  hipLaunchKernelGGL(k_zt, dim3(64), dim3(256), 0, stream, Wh, ws, out);
  hipLaunchKernelGGL(k_cspatial, dim3(896), dim3(256), 0, stream, V, out, ws);
  hipLaunchKernelGGL(k_gemm_gsp, dim3(2, 8, 32), dim3(256), 0, stream, Wgvs, Wghs, Wgvc, Wghc, Wspat, ws);
  hipLaunchKernelGGL(k_chat, dim3(2, 64), dim3(256), 0, stream, hid, Wchan, ws);
  hipLaunchKernelGGL(k_gemm_scores, dim3(40, 16), dim3(256), 0, stream, Wmlp, ws, out);
}

// Round 6
// 284.094 us; speedup vs baseline: 1.5519x; 1.1381x over previous
//
#include <hip/hip_runtime.h>

#define H 512
#define NTOK 64
#define NPIX 49
#define CDIM 2048
#define VOCAB 10000

// ws layout (float offsets). NO region requires zero-init (all plain-stored).
#define WS_S      0         // 64x512
#define WS_ST     32768     // 512x64
#define WS_HT     65536     // 512x64
#define WS_XT     98304     // 512x64
#define WS_HPT    131072    // 512x64
#define WS_FM     163840    // 8x2048
#define WS_G2F    180224    // 64x512 reduced G2
#define WS_P1     212992    // 8 kc x 64 n x 64  (h@Wg partials)
#define WS_P2     245760    // 8 kc x 64 n x 64  (s@Ws partials)
#define WS_CCH    278528    // 16 kc x 64 n x 52 (cchan partials)
#define WS_A0     331776    // 64x2048 cxt/alpha0; CSPT / CHT alias after death
#define WS_CSPT   331776
#define WS_CHT    331776
#define WS_BIG    462848    // time-shared slab window (10.2 MB):
//   phase1: sg2 slabs   24 x 32768   (st*8+kc)
//   phase2: M slabs     16 x 153664  (s*64*2401)
//   phase3: gsp slabs   32 x 32768   (st*4+kc)
//   phase4: score slabs  4 x 640000
// end = 462848 + 2560000 = 3022848 floats ~= 12.1 MB

#define OUT_ALPHA 640000
#define OUT_BETA  643136

__device__ __forceinline__ float rcp_fast(float x) {
#if __has_builtin(__builtin_amdgcn_rcpf)
  return __builtin_amdgcn_rcpf(x);
#else
  return 1.0f / x;
#endif
}
__device__ __forceinline__ float tanh_f(float x) {
  float e = __expf(2.0f * x);
  return 1.0f - 2.0f * rcp_fast(e + 1.0f);
}
__device__ __forceinline__ float sigmoid_f(float x) {
  return rcp_fast(1.0f + __expf(-x));
}

// prep: featmean (64 blocks) + transposes x/h/hprev (384 blocks)
__global__ __launch_bounds__(256) void k_prep(const float* __restrict__ x,
    const float* __restrict__ hid, const float* __restrict__ V,
    float* __restrict__ ws) {
  int bid = blockIdx.x, tid = threadIdx.x;
  if (bid < 64) {
    int b = bid >> 3, c = (bid & 7) * 256 + tid;
    float s = 0.0f;
    for (int k = 0; k < NPIX; ++k) s += V[b * NPIX * CDIM + k * CDIM + c];
    ws[WS_FM + b * CDIM + c] = s * (1.0f / NPIX);
  } else {
    int i3 = (bid - 64) * 256 + tid;
    int role = i3 >> 15, idx = i3 & 32767;
    int n = idx >> 9, k = idx & 511;
    if (role == 0)      ws[WS_XT + k * 64 + n] = x[idx];
    else if (role == 1) ws[WS_HT + k * 64 + n] = hid[idx];
    else                ws[WS_HPT + k * 64 + n] = (n & 7) ? hid[idx - 512] : 0.0f;
  }
}

// partial-slab gemm: Cslab[(n0+j)*512+c] = sum_{k0..k0+nk} A^T[k][n0+j] * W[k*512+c]
__device__ __forceinline__ void gemm16s(const float* __restrict__ A,
    const float* __restrict__ W, float* __restrict__ Cslab,
    int n0, int k0, int nk, int c) {
  float acc[16];
#pragma unroll
  for (int j = 0; j < 16; ++j) acc[j] = 0.0f;
#pragma unroll 4
  for (int kk = 0; kk < nk; ++kk) {
    int k = k0 + kk;
    float w = W[k * 512 + c];
    const float4* A4 = (const float4*)(A + k * 64 + n0);
#pragma unroll
    for (int q = 0; q < 4; ++q) {
      float4 a = A4[q];
      acc[q * 4 + 0] += a.x * w;
      acc[q * 4 + 1] += a.y * w;
      acc[q * 4 + 2] += a.z * w;
      acc[q * 4 + 3] += a.w * w;
    }
  }
#pragma unroll
  for (int j = 0; j < 16; ++j) Cslab[(n0 + j) * 512 + c] = acc[j];
}

// streams 0:(XT,Wsx) 1:(HPT,Wsh) 2:(HT,Wg2) -> slabs st*8+kc ; grid (2,8,12)
__global__ __launch_bounds__(256) void k_gemm_sg2(const float* __restrict__ Wsx,
    const float* __restrict__ Wsh, const float* __restrict__ Wg2,
    float* __restrict__ ws) {
  int c = blockIdx.x * 256 + threadIdx.x;
  int kc = blockIdx.y;
  int z = blockIdx.z, st = z >> 2, n0 = (z & 3) * 16;
  const float* A = (st == 0) ? ws + WS_XT : (st == 1) ? ws + WS_HPT : ws + WS_HT;
  const float* W = (st == 0) ? Wsx : (st == 1) ? Wsh : Wg2;
  float* C = ws + WS_BIG + (st * 8 + kc) * 32768;
  gemm16s(A, W, C, n0, kc * 64, 64, c);
}

// reduce slabs: S = sigmoid(sum slabs 0..15)*tanh(cells) -> S,ST ; G2F = sum slabs 16..23
__global__ __launch_bounds__(256) void k_act_s(const float* __restrict__ cells,
    float* __restrict__ ws) {
  int idx = blockIdx.x * 256 + threadIdx.x;
  int n = idx >> 9, c = idx & 511;
  float sa = 0.0f, g = 0.0f;
#pragma unroll
  for (int s = 0; s < 16; ++s) sa += ws[WS_BIG + s * 32768 + idx];
#pragma unroll
  for (int s = 16; s < 24; ++s) g += ws[WS_BIG + s * 32768 + idx];
  float v = sigmoid_f(sa) * tanh_f(cells[idx]);
  ws[WS_S + idx] = v;
  ws[WS_ST + c * 64 + n] = v;
  ws[WS_G2F + idx] = g;
}

// cxt[n][c] = sum_j tanh(fm[b][c]*Wfeat[j] + g2[n][j]) * Wcxt[j]
__global__ __launch_bounds__(256) void k_cxt(const float* __restrict__ Wfeat,
    const float* __restrict__ Wcxt, float* __restrict__ ws) {
  __shared__ float2 fw[512];
  __shared__ float g2l[512];
  int tid = threadIdx.x, n = blockIdx.y, b = n >> 3;
  int c = blockIdx.x * 256 + tid;
  for (int i = tid; i < 512; i += 256) {
    fw[i] = make_float2(Wfeat[i], Wcxt[i]);
    g2l[i] = ws[WS_G2F + n * H + i];
  }
  __syncthreads();
  float fm = ws[WS_FM + b * CDIM + c];
  float acc = 0.0f;
#pragma unroll 4
  for (int j = 0; j < 512; ++j) {
    float2 p = fw[j];
    acc += tanh_f(fm * p.x + g2l[j]) * p.y;
  }
  ws[WS_A0 + n * CDIM + c] = acc;
}

// bid<64: softmax over A0 row. bid>=64: cs_hwg partials (n, half), wave=kc
__global__ __launch_bounds__(256) void k_softmax_cshwg(const float* __restrict__ hid,
    const float* __restrict__ Wg, const float* __restrict__ Ws_,
    float* __restrict__ ws) {
  int bid = blockIdx.x, tid = threadIdx.x;
  if (bid < 64) {
    __shared__ float red[4];
    int n = bid, lane = tid & 63, w = tid >> 6;
    float* row = ws + WS_A0 + n * CDIM;
    float v[8];
    float m = -1e30f;
#pragma unroll
    for (int i = 0; i < 8; ++i) { v[i] = row[tid + i * 256]; m = fmaxf(m, v[i]); }
    for (int off = 32; off; off >>= 1) m = fmaxf(m, __shfl_xor(m, off));
    if (lane == 0) red[w] = m;
    __syncthreads();
    m = fmaxf(fmaxf(red[0], red[1]), fmaxf(red[2], red[3]));
    float s = 0.0f;
#pragma unroll
    for (int i = 0; i < 8; ++i) { v[i] = __expf(v[i] - m); s += v[i]; }
    for (int off = 32; off; off >>= 1) s += __shfl_xor(s, off);
    __syncthreads();
    if (lane == 0) red[w] = s;
    __syncthreads();
    s = red[0] + red[1] + red[2] + red[3];
    float inv = rcp_fast(s);
#pragma unroll
    for (int i = 0; i < 8; ++i) row[tid + i * 256] = v[i] * inv;
  } else {
    int bidx = bid - 64;
    int n = bidx & 63, half = bidx >> 6;
    int k2 = tid & 63, w = tid >> 6;
    int kc = half * 4 + w;
    const float* hrow = hid + n * H;
    const float* srow = ws + WS_S + n * H;
    float a1 = 0.0f, a2 = 0.0f;
#pragma unroll 4
    for (int kk = 0; kk < 64; ++kk) {
      int k = kc * 64 + kk;
      if (k2 < NPIX) {
        a1 += hrow[k] * Wg[k * NPIX + k2];
        a2 += srow[k] * Ws_[k * NPIX + k2];
      }
    }
    if (k2 < NPIX) {
      ws[WS_P1 + (kc * 64 + n) * 64 + k2] = a1;
      ws[WS_P2 + (kc * 64 + n) * 64 + k2] = a2;
    }
  }
}

// attnM: grid (16 cchunk, 64 n). One barrier staging; 4x4 reg tiles;
// result routed through LDS and plain-stored as a linear 2401-float partial.
__global__ __launch_bounds__(256) void k_attnM(const float* __restrict__ V,
    const float* __restrict__ Wv, float* __restrict__ ws) {
  __shared__ float vl[128 * 52];
  __shared__ float wl[128 * 52];
  int tid = threadIdx.x;
  int kc = blockIdx.x, n = blockIdx.y, b = n >> 3;
  int c0 = kc * 128;
  const float* a0 = ws + WS_A0 + n * CDIM + c0;
  const float* Vb = V + b * NPIX * CDIM + c0;
  for (int idx = tid; idx < NPIX * 128; idx += 256) {
    int k = idx >> 7, cc = idx & 127;
    vl[cc * 52 + k] = a0[cc] * Vb[k * CDIM + cc];
  }
  for (int idx = tid; idx < 128 * 64; idx += 256) {
    int cc = idx >> 6, r = idx & 63;
    if (r < NPIX) wl[cc * 52 + r] = Wv[(c0 + cc) * NPIX + r];
  }
  __syncthreads();
  // cchan partial (plain store)
  if (tid < NPIX) {
    float cch = 0.0f;
#pragma unroll 8
    for (int cc = 0; cc < 128; ++cc) cch += vl[cc * 52 + tid];
    ws[WS_CCH + (kc * 64 + n) * 52 + tid] = cch * (1.0f / CDIM);
  }
  int ti = tid >> 4, tj = tid & 15;
  float acc[4][4];
#pragma unroll
  for (int i = 0; i < 4; ++i)
#pragma unroll
    for (int j = 0; j < 4; ++j) acc[i][j] = 0.0f;
  if (ti < 13 && tj < 13) {
#pragma unroll 4
    for (int cc = 0; cc < 128; ++cc) {
      float4 a = *(const float4*)&vl[cc * 52 + 4 * ti];
      float4 w = *(const float4*)&wl[cc * 52 + 4 * tj];
      acc[0][0] += a.x * w.x; acc[0][1] += a.x * w.y; acc[0][2] += a.x * w.z; acc[0][3] += a.x * w.w;
      acc[1][0] += a.y * w.x; acc[1][1] += a.y * w.y; acc[1][2] += a.y * w.z; acc[1][3] += a.y * w.w;
      acc[2][0] += a.z * w.x; acc[2][1] += a.z * w.y; acc[2][2] += a.z * w.z; acc[2][3] += a.z * w.w;
      acc[3][0] += a.w * w.x; acc[3][1] += a.w * w.y; acc[3][2] += a.w * w.z; acc[3][3] += a.w * w.w;
    }
  }
  __syncthreads();          // vl reads done; reuse as output tile
  float* ml = vl;
  if (ti < 13 && tj < 13) {
#pragma unroll
    for (int jj = 0; jj < 4; ++jj) {
      int k2 = 4 * tj + jj;
      if (k2 < NPIX) {
#pragma unroll
        for (int ii = 0; ii < 4; ++ii) {
          int k = 4 * ti + ii;
          if (k < NPIX) ml[k2 * 49 + k] = acc[ii][jj];
        }
      }
    }
  }
  __syncthreads();
  float* Mp = ws + WS_BIG + kc * 153664 + n * 2401;
  for (int idx = tid; idx < 2401; idx += 256) Mp[idx] = ml[idx];
}

// zt: reduce P1/P2 + 16 M slabs inline; z, alpha, beta
__global__ __launch_bounds__(256) void k_zt(const float* __restrict__ Wh,
    float* __restrict__ ws, float* __restrict__ out) {
  __shared__ float gl[NPIX], cl[NPIX], whl[64];
  __shared__ float zbuf[4][64];
  int n = blockIdx.x, tid = threadIdx.x;
  if (tid < NPIX) {
    float s1 = 0.0f, s2 = 0.0f;
#pragma unroll
    for (int kc = 0; kc < 8; ++kc) {
      s1 += ws[WS_P1 + (kc * 64 + n) * 64 + tid];
      s2 += ws[WS_P2 + (kc * 64 + n) * 64 + tid];
    }
    gl[tid] = s1;
    cl[tid] = s1 + s2;
    whl[tid] = Wh[tid];
  }
  __syncthreads();
  int k = tid & 63, g = tid >> 6;
  float zp = 0.0f;
  if (k < NPIX) {
    int k2e = (g == 3) ? NPIX : (g * 13 + 13);
    const float* Mz = ws + WS_BIG + n * 2401;
    for (int k2 = g * 13; k2 < k2e; ++k2) {
      float m = 0.0f;
#pragma unroll
      for (int s = 0; s < 16; ++s) m += Mz[s * 153664 + k2 * 49 + k];
      zp += tanh_f(tanh_f(m + gl[k2])) * whl[k2];
    }
  }
  zbuf[g][k] = zp;
  __syncthreads();
  if (tid < 64) {
    int lane = tid;
    float z = zbuf[0][lane] + zbuf[1][lane] + zbuf[2][lane] + zbuf[3][lane];
    float zm = (lane < NPIX) ? z : -1e30f;
    float m1 = zm;
    for (int off = 32; off; off >>= 1) m1 = fmaxf(m1, __shfl_xor(m1, off));
    float e = (lane < NPIX) ? __expf(z - m1) : 0.0f;
    float S1 = e;
    for (int off = 32; off; off >>= 1) S1 += __shfl_xor(S1, off);
    if (lane < NPIX) out[OUT_ALPHA + n * NPIX + lane] = e * rcp_fast(S1);
    float vz = (lane < NPIX) ? tanh_f(cl[lane]) * whl[lane] : 0.0f;
    for (int off = 32; off; off >>= 1) vz += __shfl_xor(vz, off);
    if (lane == 0) {
      float ze = vz;
      float m2 = fmaxf(m1, ze);
      float S2 = S1 * __expf(m1 - m2) + __expf(ze - m2);
      out[OUT_BETA + n] = __expf(ze - m2) * rcp_fast(S2);
    }
  }
}

// c_spatial^T[d][n] = sum_k alpha_t[n][k] * V[b][k][d]
__global__ __launch_bounds__(256) void k_cspatial(const float* __restrict__ V,
    const float* __restrict__ out, float* __restrict__ ws) {
  __shared__ float al[NPIX];
  int bid = blockIdx.x, tid = threadIdx.x;
  int n = bid & 63, b = n >> 3;
  int d = (bid >> 6) * 256 + tid;
  if (tid < NPIX) al[tid] = out[OUT_ALPHA + n * NPIX + tid];
  __syncthreads();
  float s = 0.0f;
#pragma unroll 7
  for (int k = 0; k < NPIX; ++k) s += al[k] * V[b * NPIX * CDIM + k * CDIM + d];
  ws[WS_CSPT + d * 64 + n] = s;
}

// gates+spat -> slabs st*4+kc ; grid (2,4,32)
// st 0:(ST,Wgvs) 1:(HT,Wghs) 2:(ST,Wgvc) 3:(HT,Wghc) 4..7:(CSPT q, Wspat q)
__global__ __launch_bounds__(256) void k_gemm_gsp(const float* __restrict__ Wgvs,
    const float* __restrict__ Wghs, const float* __restrict__ Wgvc,
    const float* __restrict__ Wghc, const float* __restrict__ Wspat,
    float* __restrict__ ws) {
  int c = blockIdx.x * 256 + threadIdx.x;
  int kc = blockIdx.y;
  int z = blockIdx.z, st = z >> 2, n0 = (z & 3) * 16;
  const float* A;
  const float* W;
  if (st < 4) {
    A = ws + ((st & 1) ? WS_HT : WS_ST);
    W = (st == 0) ? Wgvs : (st == 1) ? Wghs : (st == 2) ? Wgvc : Wghc;
  } else {
    int q = st - 4;
    A = ws + WS_CSPT + q * 32768;
    W = Wspat + q * 262144;
  }
  float* C = ws + WS_BIG + (st * 4 + kc) * 32768;
  gemm16s(A, W, C, n0, kc * 128, 128, c);
}

// chat^T[c][n] = sigmoid(GA1)*SPAT + sigmoid(GA2)*(cchan@Wchan) + h
// reduces gsp slabs (GA1 0..7, GA2 8..15, SPAT 16..31) and 16 cchan slabs
__global__ __launch_bounds__(256) void k_chat(const float* __restrict__ hid,
    const float* __restrict__ Wchan, float* __restrict__ ws) {
  __shared__ float cl[NPIX];
  int tid = threadIdx.x, n = blockIdx.y;
  int c = blockIdx.x * 256 + tid;
  if (tid < NPIX) {
    float s = 0.0f;
#pragma unroll
    for (int kc = 0; kc < 16; ++kc) s += ws[WS_CCH + (kc * 64 + n) * 52 + tid];
    cl[tid] = s;
  }
  __syncthreads();
  float acc = 0.0f;
#pragma unroll 7
  for (int k = 0; k < NPIX; ++k) acc += cl[k] * Wchan[k * H + c];
  int idx = n * H + c;
  float ga1 = 0.0f, ga2 = 0.0f, spat = 0.0f;
#pragma unroll
  for (int s = 0; s < 8; ++s)  ga1 += ws[WS_BIG + s * 32768 + idx];
#pragma unroll
  for (int s = 8; s < 16; ++s) ga2 += ws[WS_BIG + s * 32768 + idx];
#pragma unroll
  for (int s = 16; s < 32; ++s) spat += ws[WS_BIG + s * 32768 + idx];
  float chat = sigmoid_f(ga1) * spat + sigmoid_f(ga2) * acc + hid[idx];
  ws[WS_CHT + c * 64 + n] = chat;
}

// scores partial slabs: grid (40, 4); slab[kc][n*10000+c]
__global__ __launch_bounds__(256) void k_gemm_scores(const float* __restrict__ Wmlp,
    float* __restrict__ ws) {
  int c = blockIdx.x * 256 + threadIdx.x;
  if (c >= VOCAB) return;
  int kc = blockIdx.y, k0 = kc * 128;
  const float* A = ws + WS_CHT;
  float acc[64];
#pragma unroll
  for (int n = 0; n < 64; ++n) acc[n] = 0.0f;
#pragma unroll 2
  for (int kk = 0; kk < 128; ++kk) {
    int k = k0 + kk;
    float w = Wmlp[k * VOCAB + c];
    const float4* A4 = (const float4*)(A + k * 64);
#pragma unroll
    for (int q = 0; q < 16; ++q) {
      float4 a = A4[q];
      acc[q * 4 + 0] += a.x * w;
      acc[q * 4 + 1] += a.y * w;
      acc[q * 4 + 2] += a.z * w;
      acc[q * 4 + 3] += a.w * w;
    }
  }
  float* slab = ws + WS_BIG + kc * 640000;
#pragma unroll
  for (int n = 0; n < 64; ++n) slab[n * VOCAB + c] = acc[n];
}

// out[n][c] = bmlp[c] + sum of 4 score slabs ; grid (40, 64)
__global__ __launch_bounds__(256) void k_red_scores(const float* __restrict__ bmlp,
    float* __restrict__ ws, float* __restrict__ out) {
  int c = blockIdx.x * 256 + threadIdx.x, n = blockIdx.y;
  if (c >= VOCAB) return;
  int idx = n * VOCAB + c;
  float v = bmlp[c];
#pragma unroll
  for (int s = 0; s < 4; ++s) v += ws[WS_BIG + s * 640000 + idx];
  out[idx] = v;
}

extern "C" void kernel_launch(void* const* d_in, const int* in_sizes, int n_in,
                              void* d_out, int out_size, void* d_ws, size_t ws_size,
                              hipStream_t stream) {
  const float* x     = (const float*)d_in[0];
  const float* hid   = (const float*)d_in[1];
  const float* cells = (const float*)d_in[2];
  const float* V     = (const float*)d_in[3];
  const float* Wsx   = (const float*)d_in[4];
  const float* Wsh   = (const float*)d_in[5];
  const float* Wv    = (const float*)d_in[6];
  const float* Wg    = (const float*)d_in[7];
  const float* Ws_   = (const float*)d_in[8];
  const float* Wh    = (const float*)d_in[9];
  const float* Wfeat = (const float*)d_in[10];
  const float* Wcxt  = (const float*)d_in[11];
  const float* Wg2   = (const float*)d_in[12];
  const float* Wspat = (const float*)d_in[13];
  const float* Wchan = (const float*)d_in[14];
  const float* Wgvs  = (const float*)d_in[15];
  const float* Wgvc  = (const float*)d_in[16];
  const float* Wghs  = (const float*)d_in[17];
  const float* Wghc  = (const float*)d_in[18];
  const float* Wmlp  = (const float*)d_in[19];
  const float* bmlp  = (const float*)d_in[20];
  float* ws  = (float*)d_ws;
  float* out = (float*)d_out;

  hipLaunchKernelGGL(k_prep, dim3(448), dim3(256), 0, stream, x, hid, V, ws);
  hipLaunchKernelGGL(k_gemm_sg2, dim3(2, 8, 12), dim3(256), 0, stream, Wsx, Wsh, Wg2, ws);
  hipLaunchKernelGGL(k_act_s, dim3(128), dim3(256), 0, stream, cells, ws);
  hipLaunchKernelGGL(k_cxt, dim3(8, 64), dim3(256), 0, stream, Wfeat, Wcxt, ws);
  hipLaunchKernelGGL(k_softmax_cshwg, dim3(192), dim3(256), 0, stream, hid, Wg, Ws_, ws);
  hipLaunchKernelGGL(k_attnM, dim3(16, 64), dim3(256), 0, stream, V, Wv, ws);
  hipLaunchKernelGGL(k_zt, dim3(64), dim3(256), 0, stream, Wh, ws, out);
  hipLaunchKernelGGL(k_cspatial, dim3(512), dim3(256), 0, stream, V, out, ws);
  hipLaunchKernelGGL(k_gemm_gsp, dim3(2, 4, 32), dim3(256), 0, stream, Wgvs, Wghs, Wgvc, Wghc, Wspat, ws);
  hipLaunchKernelGGL(k_chat, dim3(2, 64), dim3(256), 0, stream, hid, Wchan, ws);
  hipLaunchKernelGGL(k_gemm_scores, dim3(40, 4), dim3(256), 0, stream, Wmlp, ws);
  hipLaunchKernelGGL(k_red_scores, dim3(40, 64), dim3(256), 0, stream, bmlp, ws, out);
}

// Round 7
// 261.397 us; speedup vs baseline: 1.6866x; 1.0868x over previous
//
#include <hip/hip_runtime.h>

#define H 512
#define NTOK 64
#define NPIX 49
#define CDIM 2048
#define VOCAB 10000

// ws layout (float offsets). NO region requires zero-init (all plain-stored).
#define WS_S      0         // 64x512
#define WS_ST     32768     // 512x64
#define WS_HT     65536     // 512x64
#define WS_XT     98304     // 512x64
#define WS_HPT    131072    // 512x64
#define WS_FM     163840    // 8x2048
#define WS_G2F    180224    // 64x512 reduced G2
#define WS_P1     212992    // 8 kc x 64 n x 64  (h@Wg partials)
#define WS_P2     245760    // 8 kc x 64 n x 64  (s@Ws partials)
#define WS_CCH    278528    // 16 kc x 64 n x 52 (cchan partials)
#define WS_A0     331776    // 64x2048 cxt/alpha0; CSPT / CHT alias after death
#define WS_CSPT   331776
#define WS_CHT    331776
#define WS_BIG    462848    // time-shared slab window (10.2 MB):
//   phase1: sg2 slabs   48 x 32768   (st*16+kc)
//   phase2: M slabs     16 x 153664  (s*64*2401)
//   phase3: gsp slabs   64 x 32768   (st*8+kc)
//   phase4: score slabs  4 x 640000
// end = 462848 + 2560000 = 3022848 floats ~= 12.1 MB

#define OUT_ALPHA 640000
#define OUT_BETA  643136

__device__ __forceinline__ float rcp_fast(float x) {
#if __has_builtin(__builtin_amdgcn_rcpf)
  return __builtin_amdgcn_rcpf(x);
#else
  return 1.0f / x;
#endif
}
__device__ __forceinline__ float tanh_f(float x) {
  float e = __expf(2.0f * x);
  return 1.0f - 2.0f * rcp_fast(e + 1.0f);
}
__device__ __forceinline__ float sigmoid_f(float x) {
  return rcp_fast(1.0f + __expf(-x));
}

// prep: featmean (64 blocks) + transposes x/h/hprev (384 blocks)
__global__ __launch_bounds__(256) void k_prep(const float* __restrict__ x,
    const float* __restrict__ hid, const float* __restrict__ V,
    float* __restrict__ ws) {
  int bid = blockIdx.x, tid = threadIdx.x;
  if (bid < 64) {
    int b = bid >> 3, c = (bid & 7) * 256 + tid;
    float s = 0.0f;
    for (int k = 0; k < NPIX; ++k) s += V[b * NPIX * CDIM + k * CDIM + c];
    ws[WS_FM + b * CDIM + c] = s * (1.0f / NPIX);
  } else {
    int i3 = (bid - 64) * 256 + tid;
    int role = i3 >> 15, idx = i3 & 32767;
    int n = idx >> 9, k = idx & 511;
    if (role == 0)      ws[WS_XT + k * 64 + n] = x[idx];
    else if (role == 1) ws[WS_HT + k * 64 + n] = hid[idx];
    else                ws[WS_HPT + k * 64 + n] = (n & 7) ? hid[idx - 512] : 0.0f;
  }
}

// partial-slab gemm: Cslab[(n0+j)*512+c] = sum_{k0..k0+nk} A^T[k][n0+j] * W[k*512+c]
__device__ __forceinline__ void gemm16s(const float* __restrict__ A,
    const float* __restrict__ W, float* __restrict__ Cslab,
    int n0, int k0, int nk, int c) {
  float acc[16];
#pragma unroll
  for (int j = 0; j < 16; ++j) acc[j] = 0.0f;
#pragma unroll 4
  for (int kk = 0; kk < nk; ++kk) {
    int k = k0 + kk;
    float w = W[k * 512 + c];
    const float4* A4 = (const float4*)(A + k * 64 + n0);
#pragma unroll
    for (int q = 0; q < 4; ++q) {
      float4 a = A4[q];
      acc[q * 4 + 0] += a.x * w;
      acc[q * 4 + 1] += a.y * w;
      acc[q * 4 + 2] += a.z * w;
      acc[q * 4 + 3] += a.w * w;
    }
  }
#pragma unroll
  for (int j = 0; j < 16; ++j) Cslab[(n0 + j) * 512 + c] = acc[j];
}

// streams 0:(XT,Wsx) 1:(HPT,Wsh) 2:(HT,Wg2) -> slabs st*16+kc ; grid (2,16,12)
__global__ __launch_bounds__(256) void k_gemm_sg2(const float* __restrict__ Wsx,
    const float* __restrict__ Wsh, const float* __restrict__ Wg2,
    float* __restrict__ ws) {
  int c = blockIdx.x * 256 + threadIdx.x;
  int kc = blockIdx.y;
  int z = blockIdx.z, st = z >> 2, n0 = (z & 3) * 16;
  const float* A = (st == 0) ? ws + WS_XT : (st == 1) ? ws + WS_HPT : ws + WS_HT;
  const float* W = (st == 0) ? Wsx : (st == 1) ? Wsh : Wg2;
  float* C = ws + WS_BIG + (st * 16 + kc) * 32768;
  gemm16s(A, W, C, n0, kc * 32, 32, c);
}

// reduce slabs: S = sigmoid(sum slabs 0..31)*tanh(cells) -> S,ST ; G2F = sum slabs 32..47
__global__ __launch_bounds__(256) void k_act_s(const float* __restrict__ cells,
    float* __restrict__ ws) {
  int idx = blockIdx.x * 256 + threadIdx.x;
  int n = idx >> 9, c = idx & 511;
  float sa = 0.0f, g = 0.0f;
#pragma unroll
  for (int s = 0; s < 32; ++s) sa += ws[WS_BIG + s * 32768 + idx];
#pragma unroll
  for (int s = 32; s < 48; ++s) g += ws[WS_BIG + s * 32768 + idx];
  float v = sigmoid_f(sa) * tanh_f(cells[idx]);
  ws[WS_S + idx] = v;
  ws[WS_ST + c * 64 + n] = v;
  ws[WS_G2F + idx] = g;
}

// cxt[n][c] = sum_j tanh(fm[b][c]*Wfeat[j] + g2[n][j]) * Wcxt[j]
__global__ __launch_bounds__(256) void k_cxt(const float* __restrict__ Wfeat,
    const float* __restrict__ Wcxt, float* __restrict__ ws) {
  __shared__ float2 fw[512];
  __shared__ float g2l[512];
  int tid = threadIdx.x, n = blockIdx.y, b = n >> 3;
  int c = blockIdx.x * 256 + tid;
  for (int i = tid; i < 512; i += 256) {
    fw[i] = make_float2(Wfeat[i], Wcxt[i]);
    g2l[i] = ws[WS_G2F + n * H + i];
  }
  __syncthreads();
  float fm = ws[WS_FM + b * CDIM + c];
  float acc = 0.0f;
#pragma unroll 4
  for (int j = 0; j < 512; ++j) {
    float2 p = fw[j];
    acc += tanh_f(fm * p.x + g2l[j]) * p.y;
  }
  ws[WS_A0 + n * CDIM + c] = acc;
}

// bid<64: softmax over A0 row. bid>=64: cs_hwg partials (n, half), wave=kc
__global__ __launch_bounds__(256) void k_softmax_cshwg(const float* __restrict__ hid,
    const float* __restrict__ Wg, const float* __restrict__ Ws_,
    float* __restrict__ ws) {
  int bid = blockIdx.x, tid = threadIdx.x;
  if (bid < 64) {
    __shared__ float red[4];
    int n = bid, lane = tid & 63, w = tid >> 6;
    float* row = ws + WS_A0 + n * CDIM;
    float v[8];
    float m = -1e30f;
#pragma unroll
    for (int i = 0; i < 8; ++i) { v[i] = row[tid + i * 256]; m = fmaxf(m, v[i]); }
    for (int off = 32; off; off >>= 1) m = fmaxf(m, __shfl_xor(m, off));
    if (lane == 0) red[w] = m;
    __syncthreads();
    m = fmaxf(fmaxf(red[0], red[1]), fmaxf(red[2], red[3]));
    float s = 0.0f;
#pragma unroll
    for (int i = 0; i < 8; ++i) { v[i] = __expf(v[i] - m); s += v[i]; }
    for (int off = 32; off; off >>= 1) s += __shfl_xor(s, off);
    __syncthreads();
    if (lane == 0) red[w] = s;
    __syncthreads();
    s = red[0] + red[1] + red[2] + red[3];
    float inv = rcp_fast(s);
#pragma unroll
    for (int i = 0; i < 8; ++i) row[tid + i * 256] = v[i] * inv;
  } else {
    int bidx = bid - 64;
    int n = bidx & 63, half = bidx >> 6;
    int k2 = tid & 63, w = tid >> 6;
    int kc = half * 4 + w;
    const float* hrow = hid + n * H;
    const float* srow = ws + WS_S + n * H;
    float a1 = 0.0f, a2 = 0.0f;
#pragma unroll 4
    for (int kk = 0; kk < 64; ++kk) {
      int k = kc * 64 + kk;
      if (k2 < NPIX) {
        a1 += hrow[k] * Wg[k * NPIX + k2];
        a2 += srow[k] * Ws_[k * NPIX + k2];
      }
    }
    if (k2 < NPIX) {
      ws[WS_P1 + (kc * 64 + n) * 64 + k2] = a1;
      ws[WS_P2 + (kc * 64 + n) * 64 + k2] = a2;
    }
  }
}

// attnM: grid (16 cchunk, 64 n). One barrier staging; 4x4 reg tiles;
// result routed through LDS and plain-stored as a linear 2401-float partial.
__global__ __launch_bounds__(256) void k_attnM(const float* __restrict__ V,
    const float* __restrict__ Wv, float* __restrict__ ws) {
  __shared__ float vl[128 * 52];
  __shared__ float wl[128 * 52];
  int tid = threadIdx.x;
  int kc = blockIdx.x, n = blockIdx.y, b = n >> 3;
  int c0 = kc * 128;
  const float* a0 = ws + WS_A0 + n * CDIM + c0;
  const float* Vb = V + b * NPIX * CDIM + c0;
  for (int idx = tid; idx < NPIX * 128; idx += 256) {
    int k = idx >> 7, cc = idx & 127;
    vl[cc * 52 + k] = a0[cc] * Vb[k * CDIM + cc];
  }
  for (int idx = tid; idx < 128 * 64; idx += 256) {
    int cc = idx >> 6, r = idx & 63;
    if (r < NPIX) wl[cc * 52 + r] = Wv[(c0 + cc) * NPIX + r];
  }
  __syncthreads();
  // cchan partial (plain store)
  if (tid < NPIX) {
    float cch = 0.0f;
#pragma unroll 8
    for (int cc = 0; cc < 128; ++cc) cch += vl[cc * 52 + tid];
    ws[WS_CCH + (kc * 64 + n) * 52 + tid] = cch * (1.0f / CDIM);
  }
  int ti = tid >> 4, tj = tid & 15;
  float acc[4][4];
#pragma unroll
  for (int i = 0; i < 4; ++i)
#pragma unroll
    for (int j = 0; j < 4; ++j) acc[i][j] = 0.0f;
  if (ti < 13 && tj < 13) {
#pragma unroll 4
    for (int cc = 0; cc < 128; ++cc) {
      float4 a = *(const float4*)&vl[cc * 52 + 4 * ti];
      float4 w = *(const float4*)&wl[cc * 52 + 4 * tj];
      acc[0][0] += a.x * w.x; acc[0][1] += a.x * w.y; acc[0][2] += a.x * w.z; acc[0][3] += a.x * w.w;
      acc[1][0] += a.y * w.x; acc[1][1] += a.y * w.y; acc[1][2] += a.y * w.z; acc[1][3] += a.y * w.w;
      acc[2][0] += a.z * w.x; acc[2][1] += a.z * w.y; acc[2][2] += a.z * w.z; acc[2][3] += a.z * w.w;
      acc[3][0] += a.w * w.x; acc[3][1] += a.w * w.y; acc[3][2] += a.w * w.z; acc[3][3] += a.w * w.w;
    }
  }
  __syncthreads();          // vl reads done; reuse as output tile
  float* ml = vl;
  if (ti < 13 && tj < 13) {
#pragma unroll
    for (int jj = 0; jj < 4; ++jj) {
      int k2 = 4 * tj + jj;
      if (k2 < NPIX) {
#pragma unroll
        for (int ii = 0; ii < 4; ++ii) {
          int k = 4 * ti + ii;
          if (k < NPIX) ml[k2 * 49 + k] = acc[ii][jj];
        }
      }
    }
  }
  __syncthreads();
  float* Mp = ws + WS_BIG + kc * 153664 + n * 2401;
  for (int idx = tid; idx < 2401; idx += 256) Mp[idx] = ml[idx];
}

// zt: reduce P1/P2 + 16 M slabs inline; z, alpha, beta
__global__ __launch_bounds__(256) void k_zt(const float* __restrict__ Wh,
    float* __restrict__ ws, float* __restrict__ out) {
  __shared__ float gl[NPIX], cl[NPIX], whl[64];
  __shared__ float zbuf[4][64];
  int n = blockIdx.x, tid = threadIdx.x;
  if (tid < NPIX) {
    float s1 = 0.0f, s2 = 0.0f;
#pragma unroll
    for (int kc = 0; kc < 8; ++kc) {
      s1 += ws[WS_P1 + (kc * 64 + n) * 64 + tid];
      s2 += ws[WS_P2 + (kc * 64 + n) * 64 + tid];
    }
    gl[tid] = s1;
    cl[tid] = s1 + s2;
    whl[tid] = Wh[tid];
  }
  __syncthreads();
  int k = tid & 63, g = tid >> 6;
  float zp = 0.0f;
  if (k < NPIX) {
    int k2e = (g == 3) ? NPIX : (g * 13 + 13);
    const float* Mz = ws + WS_BIG + n * 2401;
    for (int k2 = g * 13; k2 < k2e; ++k2) {
      float m = 0.0f;
#pragma unroll
      for (int s = 0; s < 16; ++s) m += Mz[s * 153664 + k2 * 49 + k];
      zp += tanh_f(tanh_f(m + gl[k2])) * whl[k2];
    }
  }
  zbuf[g][k] = zp;
  __syncthreads();
  if (tid < 64) {
    int lane = tid;
    float z = zbuf[0][lane] + zbuf[1][lane] + zbuf[2][lane] + zbuf[3][lane];
    float zm = (lane < NPIX) ? z : -1e30f;
    float m1 = zm;
    for (int off = 32; off; off >>= 1) m1 = fmaxf(m1, __shfl_xor(m1, off));
    float e = (lane < NPIX) ? __expf(z - m1) : 0.0f;
    float S1 = e;
    for (int off = 32; off; off >>= 1) S1 += __shfl_xor(S1, off);
    if (lane < NPIX) out[OUT_ALPHA + n * NPIX + lane] = e * rcp_fast(S1);
    float vz = (lane < NPIX) ? tanh_f(cl[lane]) * whl[lane] : 0.0f;
    for (int off = 32; off; off >>= 1) vz += __shfl_xor(vz, off);
    if (lane == 0) {
      float ze = vz;
      float m2 = fmaxf(m1, ze);
      float S2 = S1 * __expf(m1 - m2) + __expf(ze - m2);
      out[OUT_BETA + n] = __expf(ze - m2) * rcp_fast(S2);
    }
  }
}

// c_spatial^T[d][n] = sum_k alpha_t[n][k] * V[b][k][d]
__global__ __launch_bounds__(256) void k_cspatial(const float* __restrict__ V,
    const float* __restrict__ out, float* __restrict__ ws) {
  __shared__ float al[NPIX];
  int bid = blockIdx.x, tid = threadIdx.x;
  int n = bid & 63, b = n >> 3;
  int d = (bid >> 6) * 256 + tid;
  if (tid < NPIX) al[tid] = out[OUT_ALPHA + n * NPIX + tid];
  __syncthreads();
  float s = 0.0f;
#pragma unroll 7
  for (int k = 0; k < NPIX; ++k) s += al[k] * V[b * NPIX * CDIM + k * CDIM + d];
  ws[WS_CSPT + d * 64 + n] = s;
}

// gates+spat -> slabs st*8+kc ; grid (2,8,32)
// st 0:(ST,Wgvs) 1:(HT,Wghs) 2:(ST,Wgvc) 3:(HT,Wghc) 4..7:(CSPT q, Wspat q)
__global__ __launch_bounds__(256) void k_gemm_gsp(const float* __restrict__ Wgvs,
    const float* __restrict__ Wghs, const float* __restrict__ Wgvc,
    const float* __restrict__ Wghc, const float* __restrict__ Wspat,
    float* __restrict__ ws) {
  int c = blockIdx.x * 256 + threadIdx.x;
  int kc = blockIdx.y;
  int z = blockIdx.z, st = z >> 2, n0 = (z & 3) * 16;
  const float* A;
  const float* W;
  if (st < 4) {
    A = ws + ((st & 1) ? WS_HT : WS_ST);
    W = (st == 0) ? Wgvs : (st == 1) ? Wghs : (st == 2) ? Wgvc : Wghc;
  } else {
    int q = st - 4;
    A = ws + WS_CSPT + q * 32768;
    W = Wspat + q * 262144;
  }
  float* C = ws + WS_BIG + (st * 8 + kc) * 32768;
  gemm16s(A, W, C, n0, kc * 64, 64, c);
}

// chat^T[c][n] = sigmoid(GA1)*SPAT + sigmoid(GA2)*(cchan@Wchan) + h
// reduces gsp slabs (GA1 0..15, GA2 16..31, SPAT 32..63) and 16 cchan slabs
__global__ __launch_bounds__(256) void k_chat(const float* __restrict__ hid,
    const float* __restrict__ Wchan, float* __restrict__ ws) {
  __shared__ float cl[NPIX];
  int tid = threadIdx.x, n = blockIdx.y;
  int c = blockIdx.x * 256 + tid;
  if (tid < NPIX) {
    float s = 0.0f;
#pragma unroll
    for (int kc = 0; kc < 16; ++kc) s += ws[WS_CCH + (kc * 64 + n) * 52 + tid];
    cl[tid] = s;
  }
  __syncthreads();
  float acc = 0.0f;
#pragma unroll 7
  for (int k = 0; k < NPIX; ++k) acc += cl[k] * Wchan[k * H + c];
  int idx = n * H + c;
  float ga1 = 0.0f, ga2 = 0.0f, spat = 0.0f;
#pragma unroll
  for (int s = 0; s < 16; ++s)  ga1 += ws[WS_BIG + s * 32768 + idx];
#pragma unroll
  for (int s = 16; s < 32; ++s) ga2 += ws[WS_BIG + s * 32768 + idx];
#pragma unroll
  for (int s = 32; s < 64; ++s) spat += ws[WS_BIG + s * 32768 + idx];
  float chat = sigmoid_f(ga1) * spat + sigmoid_f(ga2) * acc + hid[idx];
  ws[WS_CHT + c * 64 + n] = chat;
}

// scores partial slabs: grid (20, 4, 4); thread = 2 cols x 16 tokens
__global__ __launch_bounds__(256) void k_gemm_scores(const float* __restrict__ Wmlp,
    float* __restrict__ ws) {
  int tid = threadIdx.x;
  int c0 = blockIdx.x * 512 + tid * 2;
  if (c0 >= VOCAB) return;
  int kc = blockIdx.y, k0 = kc * 128;
  int n0 = blockIdx.z * 16;
  const float* A = ws + WS_CHT;
  const float2* W2 = (const float2*)Wmlp;
  int cw = c0 >> 1;
  float2 acc[16];
#pragma unroll
  for (int j = 0; j < 16; ++j) acc[j] = make_float2(0.f, 0.f);
#pragma unroll 4
  for (int kk = 0; kk < 128; ++kk) {
    int k = k0 + kk;
    float2 w = W2[k * (VOCAB / 2) + cw];
    const float4* A4 = (const float4*)(A + k * 64 + n0);
#pragma unroll
    for (int q = 0; q < 4; ++q) {
      float4 a = A4[q];
      acc[q * 4 + 0].x += a.x * w.x; acc[q * 4 + 0].y += a.x * w.y;
      acc[q * 4 + 1].x += a.y * w.x; acc[q * 4 + 1].y += a.y * w.y;
      acc[q * 4 + 2].x += a.z * w.x; acc[q * 4 + 2].y += a.z * w.y;
      acc[q * 4 + 3].x += a.w * w.x; acc[q * 4 + 3].y += a.w * w.y;
    }
  }
  float* slab = ws + WS_BIG + kc * 640000;
#pragma unroll
  for (int j = 0; j < 16; ++j)
    ((float2*)(slab + (n0 + j) * VOCAB))[cw] = acc[j];
}

// out[n][c] = bmlp[c] + sum of 4 score slabs ; grid (40, 64)
__global__ __launch_bounds__(256) void k_red_scores(const float* __restrict__ bmlp,
    float* __restrict__ ws, float* __restrict__ out) {
  int c = blockIdx.x * 256 + threadIdx.x, n = blockIdx.y;
  if (c >= VOCAB) return;
  int idx = n * VOCAB + c;
  float v = bmlp[c];
#pragma unroll
  for (int s = 0; s < 4; ++s) v += ws[WS_BIG + s * 640000 + idx];
  out[idx] = v;
}

extern "C" void kernel_launch(void* const* d_in, const int* in_sizes, int n_in,
                              void* d_out, int out_size, void* d_ws, size_t ws_size,
                              hipStream_t stream) {
  const float* x     = (const float*)d_in[0];
  const float* hid   = (const float*)d_in[1];
  const float* cells = (const float*)d_in[2];
  const float* V     = (const float*)d_in[3];
  const float* Wsx   = (const float*)d_in[4];
  const float* Wsh   = (const float*)d_in[5];
  const float* Wv    = (const float*)d_in[6];
  const float* Wg    = (const float*)d_in[7];
  const float* Ws_   = (const float*)d_in[8];
  const float* Wh    = (const float*)d_in[9];
  const float* Wfeat = (const float*)d_in[10];
  const float* Wcxt  = (const float*)d_in[11];
  const float* Wg2   = (const float*)d_in[12];
  const float* Wspat = (const float*)d_in[13];
  const float* Wchan = (const float*)d_in[14];
  const float* Wgvs  = (const float*)d_in[15];
  const float* Wgvc  = (const float*)d_in[16];
  const float* Wghs  = (const float*)d_in[17];
  const float* Wghc  = (const float*)d_in[18];
  const float* Wmlp  = (const float*)d_in[19];
  const float* bmlp  = (const float*)d_in[20];
  float* ws  = (float*)d_ws;
  float* out = (float*)d_out;

  hipLaunchKernelGGL(k_prep, dim3(448), dim3(256), 0, stream, x, hid, V, ws);
  hipLaunchKernelGGL(k_gemm_sg2, dim3(2, 16, 12), dim3(256), 0, stream, Wsx, Wsh, Wg2, ws);
  hipLaunchKernelGGL(k_act_s, dim3(128), dim3(256), 0, stream, cells, ws);
  hipLaunchKernelGGL(k_cxt, dim3(8, 64), dim3(256), 0, stream, Wfeat, Wcxt, ws);
  hipLaunchKernelGGL(k_softmax_cshwg, dim3(192), dim3(256), 0, stream, hid, Wg, Ws_, ws);
  hipLaunchKernelGGL(k_attnM, dim3(16, 64), dim3(256), 0, stream, V, Wv, ws);
  hipLaunchKernelGGL(k_zt, dim3(64), dim3(256), 0, stream, Wh, ws, out);
  hipLaunchKernelGGL(k_cspatial, dim3(512), dim3(256), 0, stream, V, out, ws);
  hipLaunchKernelGGL(k_gemm_gsp, dim3(2, 8, 32), dim3(256), 0, stream, Wgvs, Wghs, Wgvc, Wghc, Wspat, ws);
  hipLaunchKernelGGL(k_chat, dim3(2, 64), dim3(256), 0, stream, hid, Wchan, ws);
  hipLaunchKernelGGL(k_gemm_scores, dim3(20, 4, 4), dim3(256), 0, stream, Wmlp, ws);
  hipLaunchKernelGGL(k_red_scores, dim3(40, 64), dim3(256), 0, stream, bmlp, ws, out);
}